// Round 1
// baseline (898.659 us; speedup 1.0000x reference)
//
#include <hip/hip_runtime.h>

#define TT 512
#define NB 128   // batch
#define DD 128
#define HH 64
#define CC 45

__device__ __forceinline__ float sigf(float x) { return 1.0f / (1.0f + __expf(-x)); }

// ---------------------------------------------------------------------------
// GEMM: Cout[m][0:512] = A[m][0:128] @ [Wf | Wb] + [biasf | biasb]
// A: [65536][128] row-major. Wf/Wb: [128][256] row-major. Cout: [65536][512].
// BM=128, BN=128, BK=32, 256 threads, 8x8 accumulation per thread. f32 VALU.
// ---------------------------------------------------------------------------
__global__ __launch_bounds__(256) void gemm_xz(
    const float* __restrict__ A, const float* __restrict__ Wf,
    const float* __restrict__ Wb, const float* __restrict__ biasf,
    const float* __restrict__ biasb, float* __restrict__ Cout)
{
    __shared__ float As[32][132];   // [k][m], padded
    __shared__ float Bs[32][132];   // [k][n], padded
    const int tid = threadIdx.x;
    const int m0 = blockIdx.x * 128;
    const int n0 = blockIdx.y * 128;          // global col in [0,512)
    const float* W   = (n0 < 256) ? Wf : Wb;
    const float* bia = (n0 < 256) ? biasf : biasb;
    const int nc0 = n0 & 255;

    const int ty = tid >> 4, tx = tid & 15;
    const int arow = tid >> 3, akv = (tid & 7) << 2;
    const int bkr  = tid >> 5, bnv = (tid & 31) << 2;

    float acc[8][8];
    #pragma unroll
    for (int i = 0; i < 8; ++i)
        #pragma unroll
        for (int j = 0; j < 8; ++j) acc[i][j] = 0.f;

    for (int k0 = 0; k0 < 128; k0 += 32) {
        #pragma unroll
        for (int rr = 0; rr < 4; ++rr) {
            const int r = arow + rr * 32;
            const float4 av = *(const float4*)&A[(size_t)(m0 + r) * 128 + k0 + akv];
            As[akv + 0][r] = av.x; As[akv + 1][r] = av.y;
            As[akv + 2][r] = av.z; As[akv + 3][r] = av.w;
        }
        #pragma unroll
        for (int rr = 0; rr < 4; ++rr) {
            const int kr = bkr + rr * 8;
            *(float4*)&Bs[kr][bnv] =
                *(const float4*)&W[(size_t)(k0 + kr) * 256 + nc0 + bnv];
        }
        __syncthreads();
        #pragma unroll
        for (int k = 0; k < 32; ++k) {
            float av[8], bv[8];
            *(float4*)&av[0] = *(const float4*)&As[k][ty * 8];
            *(float4*)&av[4] = *(const float4*)&As[k][ty * 8 + 4];
            *(float4*)&bv[0] = *(const float4*)&Bs[k][tx * 8];
            *(float4*)&bv[4] = *(const float4*)&Bs[k][tx * 8 + 4];
            #pragma unroll
            for (int i = 0; i < 8; ++i)
                #pragma unroll
                for (int j = 0; j < 8; ++j)
                    acc[i][j] = __fmaf_rn(av[i], bv[j], acc[i][j]);
        }
        __syncthreads();
    }
    #pragma unroll
    for (int i = 0; i < 8; ++i) {
        const size_t rbase = (size_t)(m0 + ty * 8 + i) * 512 + n0 + tx * 8;
        float4 o;
        o.x = acc[i][0] + bia[nc0 + tx * 8 + 0];
        o.y = acc[i][1] + bia[nc0 + tx * 8 + 1];
        o.z = acc[i][2] + bia[nc0 + tx * 8 + 2];
        o.w = acc[i][3] + bia[nc0 + tx * 8 + 3];
        *(float4*)&Cout[rbase] = o;
        o.x = acc[i][4] + bia[nc0 + tx * 8 + 4];
        o.y = acc[i][5] + bia[nc0 + tx * 8 + 5];
        o.z = acc[i][6] + bia[nc0 + tx * 8 + 6];
        o.w = acc[i][7] + bia[nc0 + tx * 8 + 7];
        *(float4*)&Cout[rbase + 4] = o;
    }
}

// ---------------------------------------------------------------------------
// LSTM recurrence. One block per (batch, direction): 256 blocks, 256 threads.
// Thread g computes gate column g (i:0-63, f:64-127, g:128-191, o:192-255).
// U column kept in 64 VGPRs; h broadcast from LDS; wave 0 does the c/h update.
// xz: [B*T][512] (dir offset 256). hout: [B*T][128] (fwd cols 0-63, bwd 64-127).
// Backward direction reads time reversed (trow = T-1-s) and writes to trow.
// ---------------------------------------------------------------------------
__global__ __launch_bounds__(256) void lstm_rec(
    const float* __restrict__ xz, const float* __restrict__ Uf,
    const float* __restrict__ Ub, float* __restrict__ hout)
{
    const int b   = blockIdx.x & 127;
    const int dir = blockIdx.x >> 7;
    const int g   = threadIdx.x;
    const float* U = dir ? Ub : Uf;

    __shared__ float h_lds[64];
    __shared__ float z_lds[256];

    float u[64];
    #pragma unroll
    for (int k = 0; k < 64; ++k) u[k] = U[(size_t)k * 256 + g];

    if (g < 64) h_lds[g] = 0.f;
    float c = 0.f;
    __syncthreads();

    const float* xzb = xz + (size_t)b * TT * 512 + (size_t)dir * 256 + g;
    float* hob = hout + (size_t)b * TT * 128 + (size_t)dir * 64 + (g & 63);

    int trow = dir ? (TT - 1) : 0;
    const int tstep = dir ? -1 : 1;
    float xcur = xzb[(size_t)trow * 512];

    for (int s = 0; s < TT; ++s) {
        const int trnext = trow + tstep;
        float xnext = 0.f;
        if (s + 1 < TT) xnext = xzb[(size_t)trnext * 512];   // prefetch next step

        float a0 = 0.f, a1 = 0.f, a2 = 0.f, a3 = 0.f;
        #pragma unroll
        for (int k4 = 0; k4 < 64; k4 += 4) {
            const float4 hv = *(const float4*)&h_lds[k4];
            a0 = __fmaf_rn(hv.x, u[k4 + 0], a0);
            a1 = __fmaf_rn(hv.y, u[k4 + 1], a1);
            a2 = __fmaf_rn(hv.z, u[k4 + 2], a2);
            a3 = __fmaf_rn(hv.w, u[k4 + 3], a3);
        }
        const float z = xcur + ((a0 + a1) + (a2 + a3));
        z_lds[g] = z;
        __syncthreads();
        if (g < 64) {   // wave 0: gate math + state update
            const float zi = z_lds[g];
            const float zf = z_lds[64 + g];
            const float zg = z_lds[128 + g];
            const float zo = z_lds[192 + g];
            c = sigf(zf) * c + sigf(zi) * fmaxf(zg, 0.f);
            const float h = sigf(zo) * fmaxf(c, 0.f);
            h_lds[g] = h;
            hob[(size_t)trow * 128] = h;
        }
        __syncthreads();
        xcur = xnext;
        trow = trnext;
    }
}

// ---------------------------------------------------------------------------
// Dense + softmax: out[m][c] = softmax_c( h2[m][:] @ Wd[:,c] + bd[c] )
// Block: 256 threads (4 waves), 64 rows/block; Wd+bd staged in LDS once.
// Each wave handles one row per iteration; lane c<45 computes one logit.
// ---------------------------------------------------------------------------
__global__ __launch_bounds__(256) void dense_softmax(
    const float* __restrict__ h2, const float* __restrict__ Wd,
    const float* __restrict__ bd, float* __restrict__ out)
{
    __shared__ float Wl[128 * 45];
    __shared__ float bl[48];
    __shared__ float hrow[4][128];
    const int tid = threadIdx.x;
    for (int i = tid; i < 128 * 45; i += 256) Wl[i] = Wd[i];
    if (tid < 45) bl[tid] = bd[tid];
    __syncthreads();

    const int w = tid >> 6, l = tid & 63;
    const size_t row0 = (size_t)blockIdx.x * 64;
    for (int rr = 0; rr < 16; ++rr) {
        const size_t m = row0 + (size_t)rr * 4 + w;
        const float2 hv = *(const float2*)&h2[m * 128 + l * 2];
        hrow[w][l * 2] = hv.x;
        hrow[w][l * 2 + 1] = hv.y;
        __syncthreads();
        float lg = -3.0e38f;
        if (l < CC) {
            lg = bl[l];
            #pragma unroll 8
            for (int k = 0; k < 128; ++k) lg = __fmaf_rn(hrow[w][k], Wl[k * 45 + l], lg);
        }
        float mx = lg;
        #pragma unroll
        for (int off = 32; off >= 1; off >>= 1) mx = fmaxf(mx, __shfl_xor(mx, off));
        const float e = (l < CC) ? __expf(lg - mx) : 0.f;
        float sm = e;
        #pragma unroll
        for (int off = 32; off >= 1; off >>= 1) sm += __shfl_xor(sm, off);
        if (l < CC) out[m * 45 + l] = e / sm;
        __syncthreads();
    }
}

// ---------------------------------------------------------------------------
extern "C" void kernel_launch(void* const* d_in, const int* in_sizes, int n_in,
                              void* d_out, int out_size, void* d_ws, size_t ws_size,
                              hipStream_t stream)
{
    const float* x   = (const float*)d_in[0];
    const float* W1f = (const float*)d_in[1];
    const float* U1f = (const float*)d_in[2];
    const float* b1f = (const float*)d_in[3];
    const float* W1b = (const float*)d_in[4];
    const float* U1b = (const float*)d_in[5];
    const float* b1b = (const float*)d_in[6];
    const float* W2f = (const float*)d_in[7];
    const float* U2f = (const float*)d_in[8];
    const float* b2f = (const float*)d_in[9];
    const float* W2b = (const float*)d_in[10];
    const float* U2b = (const float*)d_in[11];
    const float* b2b = (const float*)d_in[12];
    const float* Wd  = (const float*)d_in[13];
    const float* bd  = (const float*)d_in[14];

    // Workspace layout (needs 160 MiB):
    //   xz : 65536 x 512 f32 = 128 MiB   (reused by layer 1 and layer 2)
    //   h  : 65536 x 128 f32 =  32 MiB   (h1, then overwritten by h2)
    float* xz = (float*)d_ws;
    float* h  = (float*)((char*)d_ws + (size_t)65536 * 512 * 4);

    const dim3 blk(256);
    const dim3 gemm_grid(512, 4);      // 65536/128 m-tiles, 512/128 n-tiles
    const dim3 rec_grid(256);          // 128 batch x 2 directions
    const dim3 dense_grid(1024);       // 65536/64 rows

    // Layer 1
    gemm_xz<<<gemm_grid, blk, 0, stream>>>(x, W1f, W1b, b1f, b1b, xz);
    lstm_rec<<<rec_grid, blk, 0, stream>>>(xz, U1f, U1b, h);
    // Layer 2
    gemm_xz<<<gemm_grid, blk, 0, stream>>>(h, W2f, W2b, b2f, b2b, xz);
    lstm_rec<<<rec_grid, blk, 0, stream>>>(xz, U2f, U2b, h);
    // Head
    dense_softmax<<<dense_grid, blk, 0, stream>>>(h, Wd, bd, (float*)d_out);
}